// Round 1
// baseline (129.919 us; speedup 1.0000x reference)
//
#include <hip/hip_runtime.h>
#include <stdint.h>
#include <math.h>

#define EMBED 4096
#define BLOCK 256    // 4 waves; wave w covers cols [256(4Q+w), +256) of quarter Q
#define NCOEF 8      // k>=9 terms: ~7e-5 in grad -> ~1e-5 in output

typedef float vfloat4 __attribute__((ext_vector_type(4)));

// Host-computed pure constants: K_k = cos(2*pi*log k)/(k-1)!  (k=1 -> 1.0)
struct CoefConsts { float k[NCOEF]; };

// single-op rotate: v_alignbit_b32 x,x,(32-r) == rotl(r)
__device__ __forceinline__ uint32_t rotl32c(uint32_t x, int r) {
  return __builtin_amdgcn_alignbit(x, x, 32 - r);
}

// One threefry round over 4 independent chains (structural ILP-4).
template <int R>
__device__ __forceinline__ void tf_round(uint32_t (&x0)[4], uint32_t (&x1)[4]) {
#pragma unroll
  for (int i = 0; i < 4; ++i) {
    x0[i] += x1[i];
    x1[i] = rotl32c(x1[i], R);
    x1[i] ^= x0[i];
  }
}
__device__ __forceinline__ void tf_inj(uint32_t (&x0)[4], uint32_t (&x1)[4],
                                       uint32_t ka, uint32_t kbc) {
#pragma unroll
  for (int i = 0; i < 4; ++i) { x0[i] += ka; x1[i] += kbc; }
}

// Quad JAX partitionable threefry2x32: key=[0,seed], counts=(0, idx), out = x0^x1.
// x1i[] must be idx + ks1 (round-0 injection pre-added).
__device__ __forceinline__ void threefry_quad(uint32_t ks1, uint32_t ks2,
                                              const uint32_t (&x1i)[4], uint32_t (&r)[4]) {
  uint32_t x0[4], x1[4];
#pragma unroll
  for (int i = 0; i < 4; ++i) { x1[i] = x1i[i]; x0[i] = 0u; }
  tf_round<13>(x0, x1); tf_round<15>(x0, x1); tf_round<26>(x0, x1); tf_round<6>(x0, x1);
  tf_inj(x0, x1, ks1, ks2 + 1u);
  tf_round<17>(x0, x1); tf_round<29>(x0, x1); tf_round<16>(x0, x1); tf_round<24>(x0, x1);
  tf_inj(x0, x1, ks2, 2u);
  tf_round<13>(x0, x1); tf_round<15>(x0, x1); tf_round<26>(x0, x1); tf_round<6>(x0, x1);
  tf_inj(x0, x1, 0u, ks1 + 3u);
  tf_round<17>(x0, x1); tf_round<29>(x0, x1); tf_round<16>(x0, x1); tf_round<24>(x0, x1);
  tf_inj(x0, x1, ks1, ks2 + 4u);
  tf_round<13>(x0, x1); tf_round<15>(x0, x1); tf_round<26>(x0, x1); tf_round<6>(x0, x1);
  tf_inj(x0, x1, ks2, 5u);
#pragma unroll
  for (int i = 0; i < 4; ++i) r[i] = x0[i] ^ x1[i];
}

// bits -> approx N(0,1) matching sqrt(2)*erfinv(2f-1+lo) to |dn| <= ~0.01
// (output sees ~0.034*dn -> invisible at 4.2e-3 threshold).
__device__ __forceinline__ float normal_from_bits(uint32_t bits) {
  const float lo = __uint_as_float(0xBF7FFFFFu);       // -(1 - 2^-24)
  float u = fmaf((float)(bits >> 9), 0x1.0p-22f, lo);  // bit-exact JAX uniform
  float t = fmaf(-u, u, 1.0f);                         // 1 - u^2  (>= 2^-24)
  float z = __builtin_amdgcn_sqrtf(-__builtin_amdgcn_logf(t));
  float r = fmaf(fmaf(fmaf(-0.001348f, z, 0.010332f), z, -0.000474f), z, 1.043458f);
  return copysignf(z * r, u);
}

// Fully fused: one block per row. Thread t handles cols 1024*Q + 4t + q, Q,q in [0,4).
// Former precompute is folded in:
//   - Horner coefs: c_j = -lam[j] * K_j (K_j host-computed double, f32 cast)
//   - seed/ks: computed from timep in-kernel
//   - av(col) = 0.1*temporal*(1 + 0.3*sin(2*pi*f*t)) computed per element via
//     hardware v_fract + v_sin (input in revolutions => sin(2*pi*x) exactly).
__global__ __launch_bounds__(BLOCK) void fused_kernel(
    const float* __restrict__ psi, const float* __restrict__ lam,
    const int* __restrict__ timep, float* __restrict__ out,
    const CoefConsts cc) {
  __shared__ float s_first[16];   // seg s covers cols [256s, 256s+256)
  __shared__ float s_last[16];
  __shared__ float s_red[4];

  const int tid = threadIdx.x;
  const int row = blockIdx.x;
  const int lane = tid & 63;
  const int wv = tid >> 6;        // 0..3

  const int tval = timep[0];
  const uint32_t ks1 = (uint32_t)((uint64_t)(int64_t)tval * 1000ull);  // threefry key
  const uint32_t ks2 = ks1 ^ 0x1BD11BDAu;

  const float tf = (float)tval;
  // (t+1)^0.2 in fp32 (ref: double pow then f32 cast; rel diff ~1e-7 -> invisible)
  const float temporal = __builtin_amdgcn_exp2f(0.2f * __builtin_amdgcn_logf(tf + 1.0f));
  const float avA = 0.1f  * temporal;   // av = avA + avB * sin(2*pi*f*t)
  const float avB = 0.03f * temporal;
  const float step = tf * (1.0f / 4096.0f);   // d(f*t)/dcol; exact for pow2 divisor

  float c[NCOEF];
  {
    const float4 l0 = *(const float4*)(lam);
    const float4 l1 = *(const float4*)(lam + 4);
    c[0] = -l0.x * cc.k[0]; c[1] = -l0.y * cc.k[1];
    c[2] = -l0.z * cc.k[2]; c[3] = -l0.w * cc.k[3];
    c[4] = -l1.x * cc.k[4]; c[5] = -l1.y * cc.k[5];
    c[6] = -l1.z * cc.k[6]; c[7] = -l1.w * cc.k[7];
  }

  const int t4 = 4 * tid;
  const float* prow = psi + (size_t)row * EMBED;

  float p[4][4];
  float xQ[4];                    // (col+1)*step at q=0 for each quarter
#pragma unroll
  for (int Q = 0; Q < 4; ++Q) {
    const float4 p4 = *(const float4*)(prow + 1024 * Q + t4);
    p[Q][0] = p4.x; p[Q][1] = p4.y; p[Q][2] = p4.z; p[Q][3] = p4.w;
    xQ[Q] = (float)(1024 * Q + t4 + 1) * step;
  }

  const uint32_t cb = (((uint32_t)row << 12) + (uint32_t)t4) + ks1;

  float fv[4][4];
  float ss = 0.0f;
#pragma unroll
  for (int q = 0; q < 4; ++q) {
    uint32_t x1i[4], bits[4];
#pragma unroll
    for (int Q = 0; Q < 4; ++Q) x1i[Q] = cb + 1024u * (uint32_t)Q + (uint32_t)q;
    threefry_quad(ks1, ks2, x1i, bits);
#pragma unroll
    for (int Q = 0; Q < 4; ++Q) {
      const float n = normal_from_bits(bits[Q]);
      float g = c[NCOEF - 1];
#pragma unroll
      for (int j = NCOEF - 2; j >= 0; --j) g = fmaf(g, p[Q][q], c[j]);
      // av(col) inline: sin(2*pi*x) via HW sin, x = (col+1)*t/4096 in revolutions
      const float sp = __builtin_amdgcn_sinf(
          __builtin_amdgcn_fractf(fmaf((float)q, step, xQ[Q])));
      const float av = fmaf(avB, sp, avA);
      const float f = fmaf(n, av, g);   // -grad + noise (coefs pre-negated)
      fv[Q][q] = f;
      ss = fmaf(f, f, ss);
    }
  }

#pragma unroll
  for (int Q = 0; Q < 4; ++Q) {
    const int s = 4 * Q + wv;
    if (lane == 0)  s_first[s] = fv[Q][0];
    if (lane == 63) s_last[s]  = fv[Q][3];
  }
#pragma unroll
  for (int off = 32; off > 0; off >>= 1) ss += __shfl_down(ss, off);
  if (lane == 0) s_red[wv] = ss;
  __syncthreads();

  const float mag = sqrtf(s_red[0] + s_red[1] + s_red[2] + s_red[3]);
  const float sc = (mag > 10.0f) ? (10.0f / (mag + 1e-8f)) : 1.0f;
  const float sc2 = 0.5f * sc;    // pre-scaled smoothing weights: 3 ops/output
  const float sc4 = 0.25f * sc;

  float* orow = out + (size_t)row * EMBED;
#pragma unroll
  for (int Q = 0; Q < 4; ++Q) {
    const int s = 4 * Q + wv;
    float lf = __shfl_up(fv[Q][3], 1);
    float rt = __shfl_down(fv[Q][0], 1);
    if (lane == 0)  lf = s_last[(s + 15) & 15];
    if (lane == 63) rt = s_first[(s + 1) & 15];
    vfloat4 o;
    o.x = fmaf(lf       + fv[Q][1], sc4, fv[Q][0] * sc2);
    o.y = fmaf(fv[Q][0] + fv[Q][2], sc4, fv[Q][1] * sc2);
    o.z = fmaf(fv[Q][1] + fv[Q][3], sc4, fv[Q][2] * sc2);
    o.w = fmaf(fv[Q][2] + rt,       sc4, fv[Q][3] * sc2);
    __builtin_nontemporal_store(o, (vfloat4*)(orow + 1024 * Q + t4));
  }
}

extern "C" void kernel_launch(void* const* d_in, const int* in_sizes, int n_in,
                              void* d_out, int out_size, void* d_ws, size_t ws_size,
                              hipStream_t stream) {
  const float* psi = (const float*)d_in[0];
  const float* lam = (const float*)d_in[1];
  const int* timep = (const int*)d_in[2];
  float* out = (float*)d_out;
  (void)in_sizes; (void)n_in; (void)out_size; (void)d_ws; (void)ws_size;

  // Pure constants (no device data): K_k = cos(2*pi*log k)/(k-1)!, same double
  // sequence as the reference, host libm == Python libm.
  CoefConsts cc;
  double fact = 1.0;
  for (int k = 1; k <= NCOEF; ++k) {
    if (k > 1) fact *= (double)(k - 1);
    const double ct = (k == 1) ? 1.0 : cos(6.283185307179586 * log((double)k));
    cc.k[k - 1] = (float)(ct / fact);
  }

  fused_kernel<<<EMBED, BLOCK, 0, stream>>>(psi, lam, timep, out, cc);
}

// Round 2
// 129.912 us; speedup vs baseline: 1.0001x; 1.0001x over previous
//
#include <hip/hip_runtime.h>
#include <stdint.h>
#include <math.h>

#define EMBED 4096
#define BLOCK 256    // 4 waves; wave w covers cols [256(4Q+w), +256) of quarter Q
#define NCOEF 8      // k>=9 terms: ~7e-5 in grad -> ~1e-5 in output

typedef float vfloat4 __attribute__((ext_vector_type(4)));

// Host-computed pure constants: K_k = cos(2*pi*log k)/(k-1)!  (k=1 -> 1.0)
struct CoefConsts { float k[NCOEF]; };

// single-op rotate: v_alignbit_b32 x,x,(32-r) == rotl(r)
__device__ __forceinline__ uint32_t rotl32c(uint32_t x, int r) {
  return __builtin_amdgcn_alignbit(x, x, 32 - r);
}

// One threefry round over 4 independent chains (structural ILP-4).
template <int R>
__device__ __forceinline__ void tf_round(uint32_t (&x0)[4], uint32_t (&x1)[4]) {
#pragma unroll
  for (int i = 0; i < 4; ++i) {
    x0[i] += x1[i];
    x1[i] = rotl32c(x1[i], R);
    x1[i] ^= x0[i];
  }
}

// First round of a block with the preceding key injection FOLDED in:
//   original:  x0 += ka; x1 += kb;  then  x0 += x1; x1 = rotl^x0
//   folded:    x1 += kb;  x0 = x0 + x1 + ka   (one v_add3_u32, 1 SGPR operand)
template <int R>
__device__ __forceinline__ void tf_round_inj(uint32_t (&x0)[4], uint32_t (&x1)[4],
                                             uint32_t ka, uint32_t kb) {
#pragma unroll
  for (int i = 0; i < 4; ++i) {
    x1[i] += kb;
    x0[i] = x0[i] + x1[i] + ka;   // v_add3_u32
    x1[i] = rotl32c(x1[i], R);
    x1[i] ^= x0[i];
  }
}

// Quad JAX partitionable threefry2x32: key=[0,seed], counts=(0, idx), out = x0^x1.
// x1i[] must be idx + ks1 (round-0 injection pre-added). Schedule identical to
// the reference cipher; injections re-associated into v_add3 (bit-exact: u32 adds).
__device__ __forceinline__ void threefry_quad(uint32_t ks1, uint32_t ks2,
                                              const uint32_t (&x1i)[4], uint32_t (&r)[4]) {
  uint32_t x0[4], x1[4];
#pragma unroll
  for (int i = 0; i < 4; ++i) {
    // round 1 with x0_init = 0:  x0 = x1i;  x1 = rotl(x1i,13) ^ x1i
    x0[i] = x1i[i];
    x1[i] = rotl32c(x1i[i], 13) ^ x1i[i];
  }
  tf_round<15>(x0, x1); tf_round<26>(x0, x1); tf_round<6>(x0, x1);
  tf_round_inj<17>(x0, x1, ks1, ks2 + 1u);   // inj(ks1, ks2+1) + round 17
  tf_round<29>(x0, x1); tf_round<16>(x0, x1); tf_round<24>(x0, x1);
  tf_round_inj<13>(x0, x1, ks2, 2u);         // inj(ks2, 2) + round 13
  tf_round<15>(x0, x1); tf_round<26>(x0, x1); tf_round<6>(x0, x1);
  tf_round_inj<17>(x0, x1, 0u, ks1 + 3u);    // inj(0, ks1+3) + round 17
  tf_round<29>(x0, x1); tf_round<16>(x0, x1); tf_round<24>(x0, x1);
  tf_round_inj<13>(x0, x1, ks1, ks2 + 4u);   // inj(ks1, ks2+4) + round 13
  tf_round<15>(x0, x1); tf_round<26>(x0, x1); tf_round<6>(x0, x1);
#pragma unroll
  for (int i = 0; i < 4; ++i) r[i] = (x0[i] + ks2) ^ (x1[i] + 5u);  // final inj + fold
}

// bits -> approx N(0,1) matching sqrt(2)*erfinv(2f-1+lo) to |dn| <= ~0.01
// (output sees ~0.034*dn -> invisible at 4.2e-3 threshold).
__device__ __forceinline__ float normal_from_bits(uint32_t bits) {
  const float lo = __uint_as_float(0xBF7FFFFFu);       // -(1 - 2^-24)
  float u = fmaf((float)(bits >> 9), 0x1.0p-22f, lo);  // bit-exact JAX uniform
  float t = fmaf(-u, u, 1.0f);                         // 1 - u^2  (>= 2^-24)
  float z = __builtin_amdgcn_sqrtf(-__builtin_amdgcn_logf(t));
  float r = fmaf(fmaf(fmaf(-0.001348f, z, 0.010332f), z, -0.000474f), z, 1.043458f);
  return copysignf(z * r, u);
}

// Fully fused: one block per row. Thread t handles cols 1024*Q + 4t + q, Q,q in [0,4).
//   - Horner coefs: c_j = -lam[j] * K_j (K_j host-computed double, f32 cast)
//   - seed/ks computed from timep in-kernel
//   - av(col): quarter-revolution identity. Quarters differ by exactly t/4 rev,
//     so sin(2*pi*(x + Q*t/4)) = +/- sin or cos of the Q=0 position, selected by
//     the wave-uniform (Q*t) mod 4. 4 sin + 4 cos total instead of 16 sin.
__global__ __launch_bounds__(BLOCK) void fused_kernel(
    const float* __restrict__ psi, const float* __restrict__ lam,
    const int* __restrict__ timep, float* __restrict__ out,
    const CoefConsts cc) {
  __shared__ float s_first[16];   // seg s covers cols [256s, 256s+256)
  __shared__ float s_last[16];
  __shared__ float s_red[4];

  const int tid = threadIdx.x;
  const int row = blockIdx.x;
  const int lane = tid & 63;
  const int wv = tid >> 6;        // 0..3

  const int tval = timep[0];
  const uint32_t ks1 = (uint32_t)((uint64_t)(int64_t)tval * 1000ull);  // threefry key
  const uint32_t ks2 = ks1 ^ 0x1BD11BDAu;

  const float tf = (float)tval;
  // (t+1)^0.2 in fp32 (ref: double pow then f32 cast; rel diff ~1e-7 -> invisible)
  const float temporal = __builtin_amdgcn_exp2f(0.2f * __builtin_amdgcn_logf(tf + 1.0f));
  const float avA = 0.1f  * temporal;   // av = avA + avB * sin(2*pi*f*t)
  const float avB = 0.03f * temporal;
  const float step = tf * (1.0f / 4096.0f);   // d(f*t)/dcol; exact pow2 divisor

  float c[NCOEF];
  {
    const float4 l0 = *(const float4*)(lam);
    const float4 l1 = *(const float4*)(lam + 4);
    c[0] = -l0.x * cc.k[0]; c[1] = -l0.y * cc.k[1];
    c[2] = -l0.z * cc.k[2]; c[3] = -l0.w * cc.k[3];
    c[4] = -l1.x * cc.k[4]; c[5] = -l1.y * cc.k[5];
    c[6] = -l1.z * cc.k[6]; c[7] = -l1.w * cc.k[7];
  }

  const int t4 = 4 * tid;
  const float* prow = psi + (size_t)row * EMBED;

  float p[4][4];
#pragma unroll
  for (int Q = 0; Q < 4; ++Q) {
    const float4 p4 = *(const float4*)(prow + 1024 * Q + t4);
    p[Q][0] = p4.x; p[Q][1] = p4.y; p[Q][2] = p4.z; p[Q][3] = p4.w;
  }

  // --- av table via quarter-revolution identity ---------------------------
  float av[4][4];
  {
    float sv[4], cv[4];
    const float x0r = (float)(t4 + 1) * step;   // Q=0, q=0 position (revolutions)
#pragma unroll
    for (int q = 0; q < 4; ++q) {
      const float fr = __builtin_amdgcn_fractf(fmaf((float)q, step, x0r));
      sv[q] = __builtin_amdgcn_sinf(fr);
      cv[q] = __builtin_amdgcn_cosf(fr);
    }
#pragma unroll
    for (int Q = 0; Q < 4; ++Q) {
      const uint32_t m = ((uint32_t)Q * (uint32_t)tval) & 3u;  // wave-uniform
      const float avBs = (m & 2u) ? -avB : avB;
      if (m & 1u) {
#pragma unroll
        for (int q = 0; q < 4; ++q) av[Q][q] = fmaf(avBs, cv[q], avA);
      } else {
#pragma unroll
        for (int q = 0; q < 4; ++q) av[Q][q] = fmaf(avBs, sv[q], avA);
      }
    }
  }

  const uint32_t cb = (((uint32_t)row << 12) + (uint32_t)t4) + ks1;

  float fv[4][4];
  float ss = 0.0f;
#pragma unroll
  for (int q = 0; q < 4; ++q) {
    uint32_t x1i[4], bits[4];
#pragma unroll
    for (int Q = 0; Q < 4; ++Q) x1i[Q] = cb + 1024u * (uint32_t)Q + (uint32_t)q;
    threefry_quad(ks1, ks2, x1i, bits);
#pragma unroll
    for (int Q = 0; Q < 4; ++Q) {
      const float n = normal_from_bits(bits[Q]);
      float g = c[NCOEF - 1];
#pragma unroll
      for (int j = NCOEF - 2; j >= 0; --j) g = fmaf(g, p[Q][q], c[j]);
      const float f = fmaf(n, av[Q][q], g);   // -grad + noise (coefs pre-negated)
      fv[Q][q] = f;
      ss = fmaf(f, f, ss);
    }
  }

#pragma unroll
  for (int Q = 0; Q < 4; ++Q) {
    const int s = 4 * Q + wv;
    if (lane == 0)  s_first[s] = fv[Q][0];
    if (lane == 63) s_last[s]  = fv[Q][3];
  }
#pragma unroll
  for (int off = 32; off > 0; off >>= 1) ss += __shfl_down(ss, off);
  if (lane == 0) s_red[wv] = ss;
  __syncthreads();

  const float mag = sqrtf(s_red[0] + s_red[1] + s_red[2] + s_red[3]);
  const float sc = (mag > 10.0f) ? (10.0f / (mag + 1e-8f)) : 1.0f;
  const float sc2 = 0.5f * sc;    // pre-scaled smoothing weights: 3 ops/output
  const float sc4 = 0.25f * sc;

  float* orow = out + (size_t)row * EMBED;
#pragma unroll
  for (int Q = 0; Q < 4; ++Q) {
    const int s = 4 * Q + wv;
    float lf = __shfl_up(fv[Q][3], 1);
    float rt = __shfl_down(fv[Q][0], 1);
    if (lane == 0)  lf = s_last[(s + 15) & 15];
    if (lane == 63) rt = s_first[(s + 1) & 15];
    vfloat4 o;
    o.x = fmaf(lf       + fv[Q][1], sc4, fv[Q][0] * sc2);
    o.y = fmaf(fv[Q][0] + fv[Q][2], sc4, fv[Q][1] * sc2);
    o.z = fmaf(fv[Q][1] + fv[Q][3], sc4, fv[Q][2] * sc2);
    o.w = fmaf(fv[Q][2] + rt,       sc4, fv[Q][3] * sc2);
    __builtin_nontemporal_store(o, (vfloat4*)(orow + 1024 * Q + t4));
  }
}

extern "C" void kernel_launch(void* const* d_in, const int* in_sizes, int n_in,
                              void* d_out, int out_size, void* d_ws, size_t ws_size,
                              hipStream_t stream) {
  const float* psi = (const float*)d_in[0];
  const float* lam = (const float*)d_in[1];
  const int* timep = (const int*)d_in[2];
  float* out = (float*)d_out;
  (void)in_sizes; (void)n_in; (void)out_size; (void)d_ws; (void)ws_size;

  // Pure constants (no device data): K_k = cos(2*pi*log k)/(k-1)!, same double
  // sequence as the reference, host libm == Python libm.
  CoefConsts cc;
  double fact = 1.0;
  for (int k = 1; k <= NCOEF; ++k) {
    if (k > 1) fact *= (double)(k - 1);
    const double ct = (k == 1) ? 1.0 : cos(6.283185307179586 * log((double)k));
    cc.k[k - 1] = (float)(ct / fact);
  }

  fused_kernel<<<EMBED, BLOCK, 0, stream>>>(psi, lam, timep, out, cc);
}